// Round 11
// baseline (176.538 us; speedup 1.0000x reference)
//
#include <hip/hip_runtime.h>

#define NUM_E   16384
#define DIM     256
#define NROWS   8192      // B*H*W
#define HW      1024      // H*W
#define BM      128
#define BN      256
#define NCB     (NUM_E / BN)   // 64 col blocks
// thresholds: bf16 pairwise noise ~2.8e-4 (7 sigma = 2e-3) + 2x key-quantization 1.22e-4
#define GATE    2.5e-3f   // flag threshold
#define TAUC    2.5e-3f   // candidate-qualify threshold
#define EHID    2.5e-3    // hidden-code margin
#define WINDOW  5e-3f     // winscan block-qualify window = 2x noise budget
#define MAXC    16

typedef __bf16 bf16x8 __attribute__((ext_vector_type(8)));
typedef float  f32x16 __attribute__((ext_vector_type(16)));

__device__ __forceinline__ unsigned short f2bf(float x) {
    unsigned u = __float_as_uint(x);
    unsigned r = (u + 0x7fffu + ((u >> 16) & 1u)) >> 16;
    return (unsigned short)r;
}
__device__ __forceinline__ int imax(int a, int b) { return a > b ? a : b; }
__device__ __forceinline__ int imin(int a, int b) { return a < b ? a : b; }
__device__ __forceinline__ bf16x8 ld16(const unsigned short* p) {
    return *(const bf16x8*)p;
}
// fragment-major address (in shorts): F[row>>5][kk>>4][lane][8],
// lane = (row&31) + 32*((kk>>3)&1); element slot kk&7.
__device__ __forceinline__ size_t faddr(int row, int kk) {
    return ((size_t)((row >> 5) * 16 + (kk >> 4))) * 512
         + ((row & 31) + ((kk >> 3) & 1) * 32) * 8 + (kk & 7);
}

// ---------------- merged pre-pass: emb norm (bid<4096) | z ssq partials ----------
__global__ void k_pre(const float* __restrict__ z, const float* __restrict__ emb,
                      float* __restrict__ zpart, float* __restrict__ inv_e,
                      double* __restrict__ se2, unsigned short* __restrict__ Eh,
                      int* __restrict__ cnt) {
    int bid = blockIdx.x;
    if (bid < NUM_E / 4) {
        if (bid == 0 && threadIdx.x == 0) { *cnt = 0; }
        int wv = threadIdx.x >> 6, lane = threadIdx.x & 63;
        int k = bid * 4 + wv;
        float4 v = *(const float4*)(emb + (size_t)k * DIM + lane * 4);
        double sq = (double)v.x*v.x + (double)v.y*v.y + (double)v.z*v.z + (double)v.w*v.w;
        for (int off = 32; off > 0; off >>= 1) sq += __shfl_down(sq, off);
        double tot = fmax(__shfl(sq, 0), 1e-24);
        if (lane == 0) { se2[k] = tot; inv_e[k] = 1.0f / fmaxf((float)sqrt(tot), 1e-12f); }
        float s = 1.0f / fmaxf((float)sqrt(tot), 1e-12f);
        ushort4 h;
        h.x = f2bf(v.x * s); h.y = f2bf(v.y * s); h.z = f2bf(v.z * s); h.w = f2bf(v.w * s);
        *(ushort4*)(Eh + faddr(k, lane * 4)) = h;   // fragment-major store
    } else {
        int ib = bid - NUM_E / 4;          // 0..511 -> (32 n-blocks, 16 c-blocks)
        int n = (ib & 31) * 256 + threadIdx.x;
        int cb = ib >> 5;
        int b = n >> 10, hw = n & 1023;
        const float* p = z + (size_t)(b * DIM + cb * 16) * HW + hw;
        float s = 0.f;
        #pragma unroll
        for (int c = 0; c < 16; c++) { float v = p[c * HW]; s += v * v; }
        zpart[cb * NROWS + n] = s;
    }
}

// ---------------- prep z: finalize inv_z in-block + bf16 frag-major store --------
__global__ void k_prep_z(const float* __restrict__ z, const float* __restrict__ zpart,
                         unsigned short* __restrict__ Zh) {
    __shared__ float T[64 * 68];
    __shared__ __align__(16) float Tinv[64];
    int t = threadIdx.x;
    int n0 = blockIdx.x * 64, c0 = blockIdx.y * 64;
    int b = n0 >> 10, hw0 = n0 & 1023;
    if (t < 64) {
        float s = 0.f;
        #pragma unroll
        for (int cb = 0; cb < 16; cb++) s += zpart[cb * NROWS + n0 + t];
        Tinv[t] = 1.0f / fmaxf(sqrtf(s), 1e-12f);
    }
    __syncthreads();
    #pragma unroll
    for (int i = 0; i < 4; i++) {
        int f = t + 256 * i;
        int cc = f >> 4, n4 = (f & 15) * 4;
        float4 v  = *(const float4*)(z + (size_t)(b * DIM + c0 + cc) * HW + hw0 + n4);
        float4 iv = *(const float4*)&Tinv[n4];
        v.x *= iv.x; v.y *= iv.y; v.z *= iv.z; v.w *= iv.w;
        *(float4*)&T[cc * 68 + n4] = v;
    }
    __syncthreads();
    #pragma unroll
    for (int i = 0; i < 4; i++) {
        int f = t + 256 * i;
        int nn = f >> 4, c4 = (f & 15) * 4;
        ushort4 h;
        h.x = f2bf(T[(c4+0)*68 + nn]);
        h.y = f2bf(T[(c4+1)*68 + nn]);
        h.z = f2bf(T[(c4+2)*68 + nn]);
        h.w = f2bf(T[(c4+3)*68 + nn]);
        *(ushort4*)(Zh + faddr(n0 + nn, c0 + c4)) = h;   // fragment-major store
    }
}

// ---------------- MFMA bf16 score: direct-to-register, FRAGMENT-MAJOR inputs ----
// (unchanged - the 71.4us winner)
__launch_bounds__(256, 2)
__global__ void k_score(const unsigned short* __restrict__ Zh,
                        const unsigned short* __restrict__ Eh, int2* __restrict__ part) {
    __shared__ __align__(16) int kv[8448];    // [64][66] int2 = 33 KB (epilogue only)
    const int t = threadIdx.x, l = t & 63, w = t >> 6;
    const int wm = w >> 1, wn = w & 1;        // wave tile 64 x 128
    int bid = blockIdx.x;
    int rr2 = (bid & 7) * 512 + (bid >> 3);
    int st = rr2 >> 6, wi = rr2 & 63;
    const int m0 = ((st >> 3) * 8 + (wi >> 3)) * BM;
    const int nb = ((st & 7) * 8 + (wi & 7)) * BN;
    const int l31 = l & 31, lh = l >> 5;

    // fragment-major bases: frag (rb, ks) at rb*16*512 + ks*512 shorts; +l*8 per lane
    const unsigned short* pa0 = Zh + ((size_t)((m0 >> 5) + wm * 2 + 0) * 16) * 512 + l * 8;
    const unsigned short* pa1 = Zh + ((size_t)((m0 >> 5) + wm * 2 + 1) * 16) * 512 + l * 8;
    const unsigned short* pb0 = Eh + ((size_t)((nb >> 5) + wn * 4 + 0) * 16) * 512 + l * 8;
    const unsigned short* pb1 = Eh + ((size_t)((nb >> 5) + wn * 4 + 1) * 16) * 512 + l * 8;
    const unsigned short* pb2 = Eh + ((size_t)((nb >> 5) + wn * 4 + 2) * 16) * 512 + l * 8;
    const unsigned short* pb3 = Eh + ((size_t)((nb >> 5) + wn * 4 + 3) * 16) * 512 + l * 8;

    f32x16 acc[2][4];
    #pragma unroll
    for (int i = 0; i < 2; i++)
        #pragma unroll
        for (int j = 0; j < 4; j++) acc[i][j] = (f32x16)2.0f;   // key bias pre-added

    bf16x8 fr[3][6];
#define LDS3(s, OFF) \
    fr[s][0] = ld16(pa0 + (OFF)); fr[s][1] = ld16(pa1 + (OFF)); \
    fr[s][2] = ld16(pb0 + (OFF)); fr[s][3] = ld16(pb1 + (OFF)); \
    fr[s][4] = ld16(pb2 + (OFF)); fr[s][5] = ld16(pb3 + (OFF));

    LDS3(0, 0); LDS3(1, 512);
    #pragma unroll
    for (int ks = 0; ks < 16; ks++) {
        const int s = ks % 3;
        if (ks + 2 < 16) { const int s2 = (ks + 2) % 3; LDS3(s2, (ks + 2) * 512); }
        __builtin_amdgcn_s_setprio(1);
        #pragma unroll
        for (int i = 0; i < 2; i++)
            #pragma unroll
            for (int j = 0; j < 4; j++)
                acc[i][j] = __builtin_amdgcn_mfma_f32_32x32x16_bf16(fr[s][i], fr[s][2 + j], acc[i][j], 0, 0, 0);
        __builtin_amdgcn_s_setprio(0);
    }
#undef LDS3

    // ---- epilogue: packed-key top-2; int2 dump, [64][66] scan ----
    const int colbase = wn * 128 + l31;
    int KA1 = 0, KA2 = 0, KB1 = 0, KB2 = 0;
    const int rl = t >> 2, q = t & 3;
    #pragma unroll
    for (int i = 0; i < 2; i++) {
        #pragma unroll
        for (int reg = 0; reg < 16; reg++) {
            int k0 = (__float_as_int(acc[i][0][reg]) & 0xFFFFFF00) | colbase;
            int k1 = (__float_as_int(acc[i][1][reg]) & 0xFFFFFF00) | (colbase + 32);
            int k2 = (__float_as_int(acc[i][2][reg]) & 0xFFFFFF00) | (colbase + 64);
            int k3 = (__float_as_int(acc[i][3][reg]) & 0xFFFFFF00) | (colbase + 96);
            int a = imax(k0, k1), b = imin(k0, k1);
            int c = imax(k2, k3), d = imin(k2, k3);
            int K1 = imax(a, c);
            int K2 = imax(imin(a, c), imax(b, d));
            int rr = wm * 32 + (reg & 3) + 8 * (reg >> 2) + 4 * lh;
            int slot = wn * 32 + l31;
            *(int2*)&kv[(rr * 66 + slot) * 2] = make_int2(K1, K2);
        }
        __syncthreads();
        int S1 = 0, S2 = 0;
        const int2* pr = (const int2*)&kv[(rl * 66 + q * 16) * 2];
        #pragma unroll
        for (int u = 0; u < 16; u++) {
            int2 e = pr[u];                  // e.x >= e.y (ordered pair)
            S2 = imax(imax(S2, e.y), imin(S1, e.x));
            S1 = imax(S1, e.x);
        }
        __syncthreads();
        #pragma unroll
        for (int d2 = 1; d2 <= 2; d2 <<= 1) {
            int o1 = __shfl_down(S1, d2), o2 = __shfl_down(S2, d2);
            S2 = imax(imax(S2, o2), imin(S1, o1));
            S1 = imax(S1, o1);
        }
        if (i == 0) { KA1 = S1; KA2 = S2; } else { KB1 = S1; KB2 = S2; }
    }
    if ((t & 3) == 0) {
        int rowA = (rl >> 5) * 64 + (rl & 31);   // i=0 rows
        int rowB = rowA + 32;                     // i=1 rows
        int seg = nb / BN;
        part[(size_t)seg * NROWS + m0 + rowA] = make_int2(KA1, KA2);
        part[(size_t)seg * NROWS + m0 + rowB] = make_int2(KB1, KB2);
    }
}

// ---------------- reduce + flag near-ties + collect block-top-2 candidates -------
__global__ void k_final(const int2* __restrict__ part, int* __restrict__ idx_ws,
                        float* __restrict__ out_idx, int* __restrict__ flags,
                        int* __restrict__ cnt, int* __restrict__ cand,
                        int* __restrict__ ccnt, float* __restrict__ v2q,
                        int* __restrict__ bm) {
    __shared__ int rK1[8][33], rK2[8][33], rS[8][33];
    __shared__ int bK1[32], bK2[32];
    __shared__ int lcc[32];
    __shared__ int lcand[32][MAXC];
    __shared__ int sv2[8][33];
    const int nl = threadIdx.x & 31, sc = threadIdx.x >> 5;
    const int n = blockIdx.x * 32 + nl;
    if (threadIdx.x < 32) lcc[threadIdx.x] = 0;
    int K1 = 0, K2 = 0, S1 = 0;
    for (int s = sc * 8; s < sc * 8 + 8; s++) {
        int2 e = part[(size_t)s * NROWS + n];
        S1 = (e.x > K1) ? s : S1;
        int nK2 = imax(imin(K1, e.x), imax(K2, e.y));
        K1 = imax(K1, e.x);
        K2 = nK2;
    }
    rK1[sc][nl] = K1; rK2[sc][nl] = K2; rS[sc][nl] = S1;
    __syncthreads();
    if (threadIdx.x < 32) {
        int W1 = 0, W2 = 0, WS = 0;
        #pragma unroll
        for (int s2 = 0; s2 < 8; s2++) {
            int e1 = rK1[s2][threadIdx.x], e2 = rK2[s2][threadIdx.x];
            WS = (e1 > W1) ? rS[s2][threadIdx.x] : WS;
            int nW2 = imax(imin(W1, e1), imax(W2, e2));
            W1 = imax(W1, e1);
            W2 = nW2;
        }
        int nn = blockIdx.x * 32 + threadIdx.x;
        int J1 = WS * BN + (W1 & 0xFF);
        idx_ws[nn] = J1;
        out_idx[nn] = (float)J1;
        bK1[threadIdx.x] = W1;
        bK2[threadIdx.x] = W2;
        bm[nn] = 0;
    }
    __syncthreads();
    int kthr = __float_as_int(__int_as_float(bK1[nl] & 0xFFFFFF00) - TAUC);
    int lv2 = 0;
    for (int s = sc * 8; s < sc * 8 + 8; s++) {
        int2 e = part[(size_t)s * NROWS + n];
        if (e.x >= kthr) {
            int pos = atomicAdd(&lcc[nl], 2);
            if (pos < MAXC)     lcand[nl][pos]     = s * BN + (e.x & 0xFF);
            if (pos + 1 < MAXC) lcand[nl][pos + 1] = s * BN + (e.y & 0xFF);
            lv2 = imax(lv2, e.y);
        }
    }
    sv2[sc][nl] = lv2;
    __syncthreads();
    if (threadIdx.x < 32) {
        int nn = blockIdx.x * 32 + threadIdx.x;
        float v1 = __int_as_float(bK1[threadIdx.x] & 0xFFFFFF00) - 2.0f;
        float v2 = __int_as_float(bK2[threadIdx.x] & 0xFFFFFF00) - 2.0f;
        if (v1 - v2 < GATE) {
            int m = 0;
            #pragma unroll
            for (int s2 = 0; s2 < 8; s2++) m = imax(m, sv2[s2][threadIdx.x]);
            int p = atomicAdd(cnt, 1);
            flags[p] = nn;
            ccnt[nn] = lcc[threadIdx.x];
            v2q[nn] = __int_as_float(m & 0xFFFFFF00) - 2.0f;
            #pragma unroll
            for (int j = 0; j < MAXC; j++) cand[nn * MAXC + j] = lcand[threadIdx.x][j];
        }
    }
}

// ---------------- merged rescue: fp64 cand-rescan + inline window-pruned rescan --
// One block per flagged row (grid-stride). Phase A: fp64 rescore of collected
// candidates (= old k_rescan_cand). If unresolved (C>MAXC or hidden-code margin),
// Phase B runs the window-pruned full rescan (= old k_winscan) IMMEDIATELY, with
// zs already resident - the two stages were serial across a launch boundary
// before, so no parallelism is lost; one launch + flags2 indirection + a 256-line
// z re-gather per escaped row are eliminated.
__launch_bounds__(256)
__global__ void k_rescue(const int* __restrict__ flags, const int* __restrict__ cnt,
                         const int* __restrict__ cand, const int* __restrict__ ccnt,
                         const float* __restrict__ v2q, const int2* __restrict__ part,
                         const float* __restrict__ z, const float* __restrict__ emb,
                         const double* __restrict__ se2, const float* __restrict__ inv_e,
                         int* __restrict__ idx_ws, float* __restrict__ out_idx,
                         unsigned long long* __restrict__ slot, int* __restrict__ bm) {
    __shared__ double zs[DIM];
    __shared__ __align__(16) float zsf[DIM];
    __shared__ double wv[4];
    __shared__ int    wi[4];
    __shared__ int    sK1[64], sK2[64];
    __shared__ unsigned long long wbest[4];
    __shared__ int escFlag;
    const int t = threadIdx.x, l = t & 63, w = t >> 6;
    const int F = *cnt;
    for (int f = blockIdx.x; f < F; f += gridDim.x) {
        int n = flags[f];
        int C = ccnt[n];
        int b = n >> 10, hw = n & 1023;
        __syncthreads();
        double zv = (double)z[(size_t)(b * DIM + t) * HW + hw];
        zs[t] = zv; zsf[t] = (float)zv;
        if (t < 64) {
            int2 e = part[(size_t)t * NROWS + n];
            sK1[t] = e.x; sK2[t] = e.y;
        }
        __syncthreads();
        // ---- phase A: fp64 rescore of candidates ----
        double best = -2e18; int bi = 0x7fffffff;
        if (C <= MAXC) {
            double z0 = zs[l*4], z1 = zs[l*4+1], z2 = zs[l*4+2], z3 = zs[l*4+3];
            for (int cix = w; cix < C; cix += 4) {
                int k = cand[n * MAXC + cix];
                float4 ev = *(const float4*)(emb + (size_t)k * DIM + l * 4);
                double d = z0 * (double)ev.x + z1 * (double)ev.y
                         + z2 * (double)ev.z + z3 * (double)ev.w;
                #pragma unroll
                for (int o = 32; o > 0; o >>= 1) d += __shfl_down(d, o);
                if (l == 0) {
                    double qv = d / sqrt(se2[k]);
                    if (qv > best || (qv == best && k < bi)) { best = qv; bi = k; }
                }
            }
        }
        if (l == 0) { wv[w] = best; wi[w] = bi; }
        __syncthreads();
        if (t == 0) {
            bool esc = (C > MAXC);
            if (!esc) {
                double B = wv[0]; int BI = wi[0];
                #pragma unroll
                for (int x = 1; x < 4; x++)
                    if (wv[x] > B || (wv[x] == B && wi[x] < BI)) { B = wv[x]; BI = wi[x]; }
                if ((double)v2q[n] >= B - EHID) {
                    esc = true;                       // possible hidden code
                } else {
                    idx_ws[n] = BI; out_idx[n] = (float)BI;
                }
            }
            escFlag = esc ? 1 : 0;
            if (esc) bm[n] = 1;
        }
        __syncthreads();
        // ---- phase B: window-pruned rescan (only if escaped) ----
        if (escFlag) {
            int K1 = 0;
            #pragma unroll
            for (int s = 0; s < 64; s++) K1 = imax(K1, sK1[s]);
            float cosW1 = __int_as_float(K1 & 0xFFFFFF00) - 2.0f;
            int thr = __float_as_int((cosW1 - WINDOW) + 2.0f) & 0xFFFFFF00;
            unsigned long long bestk = 0ull;
            for (int s = 0; s < 64; s++) {
                if (imax(sK1[s], sK2[s]) < thr) continue;   // wave-uniform (LDS)
                int k = s * 256 + t;
                const float4* er = (const float4*)(emb + (size_t)k * DIM);
                float d0 = 0.f, d1 = 0.f, d2 = 0.f, d3 = 0.f;
                #pragma unroll
                for (int d4 = 0; d4 < 64; d4++) {
                    float4 ev = er[d4];
                    float4 zv4 = *(const float4*)&zsf[d4 * 4];
                    d0 += zv4.x * ev.x; d1 += zv4.y * ev.y;
                    d2 += zv4.z * ev.z; d3 += zv4.w * ev.w;
                }
                float qv = ((d0 + d1) + (d2 + d3)) * inv_e[k];
                unsigned long long key =
                    (((unsigned long long)__float_as_uint(qv + 32.0f)) << 14)
                    | (unsigned long long)(0x3FFF - k);     // tie -> lowest k
                bestk = key > bestk ? key : bestk;
            }
            #pragma unroll
            for (int o = 32; o > 0; o >>= 1) {
                unsigned long long ob = __shfl_down(bestk, o);
                bestk = ob > bestk ? ob : bestk;
            }
            if (l == 0) wbest[w] = bestk;
            __syncthreads();
            if (t == 0) {
                unsigned long long B = wbest[0];
                #pragma unroll
                for (int x = 1; x < 4; x++) B = wbest[x] > B ? wbest[x] : B;
                slot[n] = B;
            }
        }
    }
}

// ---------------- gather z_q = emb[idx] * inv_e[idx]; decode rescued rows --------
__global__ void k_zq(const int* __restrict__ idx_ws, const float* __restrict__ emb,
                     const float* __restrict__ inv_e, float* __restrict__ zq,
                     const int* __restrict__ bm, const unsigned long long* __restrict__ slot,
                     float* __restrict__ out_idx) {
    int t = threadIdx.x;
    int n = blockIdx.x * 256 + t;
    int b = n >> 10, hw = n & 1023;
    int c0 = blockIdx.y * 32;
    int id = idx_ws[n];
    if (bm[n]) {
        id = 0x3FFF - (int)(slot[n] & 0x3FFFull);
        if (blockIdx.y == 0) out_idx[n] = (float)id;
    }
    float s = inv_e[id];
    const float* er = emb + (size_t)id * DIM;
    #pragma unroll
    for (int cc = 0; cc < 32; cc += 4) {
        float4 a = *(const float4*)(er + c0 + cc);
        zq[(size_t)(b * DIM + c0 + cc + 0) * HW + hw] = a.x * s;
        zq[(size_t)(b * DIM + c0 + cc + 1) * HW + hw] = a.y * s;
        zq[(size_t)(b * DIM + c0 + cc + 2) * HW + hw] = a.z * s;
        zq[(size_t)(b * DIM + c0 + cc + 3) * HW + hw] = a.w * s;
    }
}

extern "C" void kernel_launch(void* const* d_in, const int* in_sizes, int n_in,
                              void* d_out, int out_size, void* d_ws, size_t ws_size,
                              hipStream_t stream) {
    const float* z   = (const float*)d_in[0];
    const float* emb = (const float*)d_in[1];

    unsigned short* Zh = (unsigned short*)d_ws;           // 4 MB (fragment-major)
    unsigned short* Eh = Zh + (size_t)NROWS * DIM;        // 8 MB (fragment-major)
    float*  inv_e = (float*)(Eh + (size_t)NUM_E * DIM);   // 64 KB
    float*  zpart = inv_e + NUM_E;                        // 512 KB (reused as slot later)
    int*    idx_ws = (int*)(zpart + 16 * NROWS);          // 32 KB
    double* se2   = (double*)(idx_ws + NROWS);            // 128 KB
    int*    flags = (int*)(se2 + NUM_E);                  // 32 KB
    int*    cand  = flags + NROWS;                        // 512 KB (16/row)
    int*    ccnt  = cand + NROWS * MAXC;                  // 32 KB
    float*  v2q   = (float*)(ccnt + NROWS);               // 32 KB
    int*    bm    = (int*)(v2q + NROWS);                  // 32 KB (rescue bitmap)
    int*    cnt   = bm + NROWS;                           // 4 B
    unsigned long long* slot = (unsigned long long*)zpart; // 64 KB, reuses zpart

    float* zq      = (float*)d_out;
    float* out_idx = zq + (size_t)NROWS * DIM;
    // part (4 MB: 64 segs x 8192 rows x int2) aliases the z_q region's first half;
    // consumed by k_final + k_rescue, then overwritten by k_zq.
    int2* part = (int2*)zq;

    k_pre    <<<NUM_E / 4 + 512, 256, 0, stream>>>(z, emb, zpart, inv_e, se2, Eh, cnt);
    k_prep_z <<<dim3(NROWS / 64, DIM / 64), 256, 0, stream>>>(z, zpart, Zh);
    k_score  <<<(NROWS / BM) * NCB, 256, 0, stream>>>(Zh, Eh, part);
    k_final  <<<NROWS / 32, 256, 0, stream>>>(part, idx_ws, out_idx, flags, cnt,
                                              cand, ccnt, v2q, bm);
    k_rescue <<<1024, 256, 0, stream>>>(flags, cnt, cand, ccnt, v2q, part, z, emb,
                                        se2, inv_e, idx_ws, out_idx, slot, bm);
    k_zq     <<<dim3(NROWS / 256, 8), 256, 0, stream>>>(idx_ws, emb, inv_e, zq,
                                                        bm, slot, out_idx);
}

// Round 12
// 169.159 us; speedup vs baseline: 1.0436x; 1.0436x over previous
//
#include <hip/hip_runtime.h>

#define NUM_E   16384
#define DIM     256
#define NROWS   8192      // B*H*W
#define HW      1024      // H*W
#define BM      128
#define BN      256
#define NCB     (NUM_E / BN)   // 64 col blocks
// thresholds: bf16 pairwise noise ~2.8e-4 (7 sigma = 2e-3) + 2x key-quantization 1.22e-4
#define GATE    2.5e-3f   // flag threshold
#define TAUC    2.5e-3f   // candidate-qualify threshold
#define EHID    2.5e-3    // hidden-code margin
#define WINDOW  5e-3f     // winscan block-qualify window = 2x noise budget
#define MAXC    16

typedef __bf16 bf16x8 __attribute__((ext_vector_type(8)));
typedef float  f32x16 __attribute__((ext_vector_type(16)));

__device__ __forceinline__ unsigned short f2bf(float x) {
    unsigned u = __float_as_uint(x);
    unsigned r = (u + 0x7fffu + ((u >> 16) & 1u)) >> 16;
    return (unsigned short)r;
}
__device__ __forceinline__ int imax(int a, int b) { return a > b ? a : b; }
__device__ __forceinline__ int imin(int a, int b) { return a < b ? a : b; }
__device__ __forceinline__ bf16x8 ld16(const unsigned short* p) {
    return *(const bf16x8*)p;
}
// fragment-major address (in shorts): F[row>>5][kk>>4][lane][8],
// lane = (row&31) + 32*((kk>>3)&1); element slot kk&7.
__device__ __forceinline__ size_t faddr(int row, int kk) {
    return ((size_t)((row >> 5) * 16 + (kk >> 4))) * 512
         + ((row & 31) + ((kk >> 3) & 1) * 32) * 8 + (kk & 7);
}

// ---------------- merged pre-pass: emb norm (bid<4096) | z ssq partials ----------
__global__ void k_pre(const float* __restrict__ z, const float* __restrict__ emb,
                      float* __restrict__ zpart, float* __restrict__ inv_e,
                      double* __restrict__ se2, unsigned short* __restrict__ Eh,
                      int* __restrict__ cnt, int* __restrict__ cnt2) {
    int bid = blockIdx.x;
    if (bid < NUM_E / 4) {
        if (bid == 0 && threadIdx.x == 0) { *cnt = 0; *cnt2 = 0; }
        int wv = threadIdx.x >> 6, lane = threadIdx.x & 63;
        int k = bid * 4 + wv;
        float4 v = *(const float4*)(emb + (size_t)k * DIM + lane * 4);
        double sq = (double)v.x*v.x + (double)v.y*v.y + (double)v.z*v.z + (double)v.w*v.w;
        for (int off = 32; off > 0; off >>= 1) sq += __shfl_down(sq, off);
        double tot = fmax(__shfl(sq, 0), 1e-24);
        if (lane == 0) { se2[k] = tot; inv_e[k] = 1.0f / fmaxf((float)sqrt(tot), 1e-12f); }
        float s = 1.0f / fmaxf((float)sqrt(tot), 1e-12f);
        ushort4 h;
        h.x = f2bf(v.x * s); h.y = f2bf(v.y * s); h.z = f2bf(v.z * s); h.w = f2bf(v.w * s);
        *(ushort4*)(Eh + faddr(k, lane * 4)) = h;   // fragment-major store
    } else {
        int ib = bid - NUM_E / 4;          // 0..511 -> (32 n-blocks, 16 c-blocks)
        int n = (ib & 31) * 256 + threadIdx.x;
        int cb = ib >> 5;
        int b = n >> 10, hw = n & 1023;
        const float* p = z + (size_t)(b * DIM + cb * 16) * HW + hw;
        float s = 0.f;
        #pragma unroll
        for (int c = 0; c < 16; c++) { float v = p[c * HW]; s += v * v; }
        zpart[cb * NROWS + n] = s;
    }
}

// ---------------- prep z: finalize inv_z in-block + bf16 frag-major store --------
__global__ void k_prep_z(const float* __restrict__ z, const float* __restrict__ zpart,
                         unsigned short* __restrict__ Zh) {
    __shared__ float T[64 * 68];
    __shared__ __align__(16) float Tinv[64];
    int t = threadIdx.x;
    int n0 = blockIdx.x * 64, c0 = blockIdx.y * 64;
    int b = n0 >> 10, hw0 = n0 & 1023;
    if (t < 64) {
        float s = 0.f;
        #pragma unroll
        for (int cb = 0; cb < 16; cb++) s += zpart[cb * NROWS + n0 + t];
        Tinv[t] = 1.0f / fmaxf(sqrtf(s), 1e-12f);
    }
    __syncthreads();
    #pragma unroll
    for (int i = 0; i < 4; i++) {
        int f = t + 256 * i;
        int cc = f >> 4, n4 = (f & 15) * 4;
        float4 v  = *(const float4*)(z + (size_t)(b * DIM + c0 + cc) * HW + hw0 + n4);
        float4 iv = *(const float4*)&Tinv[n4];
        v.x *= iv.x; v.y *= iv.y; v.z *= iv.z; v.w *= iv.w;
        *(float4*)&T[cc * 68 + n4] = v;
    }
    __syncthreads();
    #pragma unroll
    for (int i = 0; i < 4; i++) {
        int f = t + 256 * i;
        int nn = f >> 4, c4 = (f & 15) * 4;
        ushort4 h;
        h.x = f2bf(T[(c4+0)*68 + nn]);
        h.y = f2bf(T[(c4+1)*68 + nn]);
        h.z = f2bf(T[(c4+2)*68 + nn]);
        h.w = f2bf(T[(c4+3)*68 + nn]);
        *(ushort4*)(Zh + faddr(n0 + nn, c0 + c4)) = h;   // fragment-major store
    }
}

// ---------------- MFMA bf16 score: direct-to-register, FRAGMENT-MAJOR inputs ----
// (unchanged - the 71.4us winner)
__launch_bounds__(256, 2)
__global__ void k_score(const unsigned short* __restrict__ Zh,
                        const unsigned short* __restrict__ Eh, int2* __restrict__ part) {
    __shared__ __align__(16) int kv[8448];    // [64][66] int2 = 33 KB (epilogue only)
    const int t = threadIdx.x, l = t & 63, w = t >> 6;
    const int wm = w >> 1, wn = w & 1;        // wave tile 64 x 128
    int bid = blockIdx.x;
    int rr2 = (bid & 7) * 512 + (bid >> 3);
    int st = rr2 >> 6, wi = rr2 & 63;
    const int m0 = ((st >> 3) * 8 + (wi >> 3)) * BM;
    const int nb = ((st & 7) * 8 + (wi & 7)) * BN;
    const int l31 = l & 31, lh = l >> 5;

    // fragment-major bases: frag (rb, ks) at rb*16*512 + ks*512 shorts; +l*8 per lane
    const unsigned short* pa0 = Zh + ((size_t)((m0 >> 5) + wm * 2 + 0) * 16) * 512 + l * 8;
    const unsigned short* pa1 = Zh + ((size_t)((m0 >> 5) + wm * 2 + 1) * 16) * 512 + l * 8;
    const unsigned short* pb0 = Eh + ((size_t)((nb >> 5) + wn * 4 + 0) * 16) * 512 + l * 8;
    const unsigned short* pb1 = Eh + ((size_t)((nb >> 5) + wn * 4 + 1) * 16) * 512 + l * 8;
    const unsigned short* pb2 = Eh + ((size_t)((nb >> 5) + wn * 4 + 2) * 16) * 512 + l * 8;
    const unsigned short* pb3 = Eh + ((size_t)((nb >> 5) + wn * 4 + 3) * 16) * 512 + l * 8;

    f32x16 acc[2][4];
    #pragma unroll
    for (int i = 0; i < 2; i++)
        #pragma unroll
        for (int j = 0; j < 4; j++) acc[i][j] = (f32x16)2.0f;   // key bias pre-added

    bf16x8 fr[3][6];
#define LDS3(s, OFF) \
    fr[s][0] = ld16(pa0 + (OFF)); fr[s][1] = ld16(pa1 + (OFF)); \
    fr[s][2] = ld16(pb0 + (OFF)); fr[s][3] = ld16(pb1 + (OFF)); \
    fr[s][4] = ld16(pb2 + (OFF)); fr[s][5] = ld16(pb3 + (OFF));

    LDS3(0, 0); LDS3(1, 512);
    #pragma unroll
    for (int ks = 0; ks < 16; ks++) {
        const int s = ks % 3;
        if (ks + 2 < 16) { const int s2 = (ks + 2) % 3; LDS3(s2, (ks + 2) * 512); }
        __builtin_amdgcn_s_setprio(1);
        #pragma unroll
        for (int i = 0; i < 2; i++)
            #pragma unroll
            for (int j = 0; j < 4; j++)
                acc[i][j] = __builtin_amdgcn_mfma_f32_32x32x16_bf16(fr[s][i], fr[s][2 + j], acc[i][j], 0, 0, 0);
        __builtin_amdgcn_s_setprio(0);
    }
#undef LDS3

    // ---- epilogue: packed-key top-2; int2 dump, [64][66] scan ----
    const int colbase = wn * 128 + l31;
    int KA1 = 0, KA2 = 0, KB1 = 0, KB2 = 0;
    const int rl = t >> 2, q = t & 3;
    #pragma unroll
    for (int i = 0; i < 2; i++) {
        #pragma unroll
        for (int reg = 0; reg < 16; reg++) {
            int k0 = (__float_as_int(acc[i][0][reg]) & 0xFFFFFF00) | colbase;
            int k1 = (__float_as_int(acc[i][1][reg]) & 0xFFFFFF00) | (colbase + 32);
            int k2 = (__float_as_int(acc[i][2][reg]) & 0xFFFFFF00) | (colbase + 64);
            int k3 = (__float_as_int(acc[i][3][reg]) & 0xFFFFFF00) | (colbase + 96);
            int a = imax(k0, k1), b = imin(k0, k1);
            int c = imax(k2, k3), d = imin(k2, k3);
            int K1 = imax(a, c);
            int K2 = imax(imin(a, c), imax(b, d));
            int rr = wm * 32 + (reg & 3) + 8 * (reg >> 2) + 4 * lh;
            int slot = wn * 32 + l31;
            *(int2*)&kv[(rr * 66 + slot) * 2] = make_int2(K1, K2);
        }
        __syncthreads();
        int S1 = 0, S2 = 0;
        const int2* pr = (const int2*)&kv[(rl * 66 + q * 16) * 2];
        #pragma unroll
        for (int u = 0; u < 16; u++) {
            int2 e = pr[u];                  // e.x >= e.y (ordered pair)
            S2 = imax(imax(S2, e.y), imin(S1, e.x));
            S1 = imax(S1, e.x);
        }
        __syncthreads();
        #pragma unroll
        for (int d2 = 1; d2 <= 2; d2 <<= 1) {
            int o1 = __shfl_down(S1, d2), o2 = __shfl_down(S2, d2);
            S2 = imax(imax(S2, o2), imin(S1, o1));
            S1 = imax(S1, o1);
        }
        if (i == 0) { KA1 = S1; KA2 = S2; } else { KB1 = S1; KB2 = S2; }
    }
    if ((t & 3) == 0) {
        int rowA = (rl >> 5) * 64 + (rl & 31);   // i=0 rows
        int rowB = rowA + 32;                     // i=1 rows
        int seg = nb / BN;
        part[(size_t)seg * NROWS + m0 + rowA] = make_int2(KA1, KA2);
        part[(size_t)seg * NROWS + m0 + rowB] = make_int2(KB1, KB2);
    }
}

// ---------------- reduce + flag near-ties + collect block-top-2 candidates -------
__global__ void k_final(const int2* __restrict__ part, int* __restrict__ idx_ws,
                        float* __restrict__ out_idx, int* __restrict__ flags,
                        int* __restrict__ cnt, int* __restrict__ cand,
                        int* __restrict__ ccnt, float* __restrict__ v2q,
                        int* __restrict__ bm) {
    __shared__ int rK1[8][33], rK2[8][33], rS[8][33];
    __shared__ int bK1[32], bK2[32];
    __shared__ int lcc[32];
    __shared__ int lcand[32][MAXC];
    __shared__ int sv2[8][33];
    const int nl = threadIdx.x & 31, sc = threadIdx.x >> 5;
    const int n = blockIdx.x * 32 + nl;
    if (threadIdx.x < 32) lcc[threadIdx.x] = 0;
    int K1 = 0, K2 = 0, S1 = 0;
    for (int s = sc * 8; s < sc * 8 + 8; s++) {
        int2 e = part[(size_t)s * NROWS + n];
        S1 = (e.x > K1) ? s : S1;
        int nK2 = imax(imin(K1, e.x), imax(K2, e.y));
        K1 = imax(K1, e.x);
        K2 = nK2;
    }
    rK1[sc][nl] = K1; rK2[sc][nl] = K2; rS[sc][nl] = S1;
    __syncthreads();
    if (threadIdx.x < 32) {
        int W1 = 0, W2 = 0, WS = 0;
        #pragma unroll
        for (int s2 = 0; s2 < 8; s2++) {
            int e1 = rK1[s2][threadIdx.x], e2 = rK2[s2][threadIdx.x];
            WS = (e1 > W1) ? rS[s2][threadIdx.x] : WS;
            int nW2 = imax(imin(W1, e1), imax(W2, e2));
            W1 = imax(W1, e1);
            W2 = nW2;
        }
        int nn = blockIdx.x * 32 + threadIdx.x;
        int J1 = WS * BN + (W1 & 0xFF);
        idx_ws[nn] = J1;
        out_idx[nn] = (float)J1;
        bK1[threadIdx.x] = W1;
        bK2[threadIdx.x] = W2;
        bm[nn] = 0;
    }
    __syncthreads();
    int kthr = __float_as_int(__int_as_float(bK1[nl] & 0xFFFFFF00) - TAUC);
    int lv2 = 0;
    for (int s = sc * 8; s < sc * 8 + 8; s++) {
        int2 e = part[(size_t)s * NROWS + n];
        if (e.x >= kthr) {
            int pos = atomicAdd(&lcc[nl], 2);
            if (pos < MAXC)     lcand[nl][pos]     = s * BN + (e.x & 0xFF);
            if (pos + 1 < MAXC) lcand[nl][pos + 1] = s * BN + (e.y & 0xFF);
            lv2 = imax(lv2, e.y);
        }
    }
    sv2[sc][nl] = lv2;
    __syncthreads();
    if (threadIdx.x < 32) {
        int nn = blockIdx.x * 32 + threadIdx.x;
        float v1 = __int_as_float(bK1[threadIdx.x] & 0xFFFFFF00) - 2.0f;
        float v2 = __int_as_float(bK2[threadIdx.x] & 0xFFFFFF00) - 2.0f;
        if (v1 - v2 < GATE) {
            int m = 0;
            #pragma unroll
            for (int s2 = 0; s2 < 8; s2++) m = imax(m, sv2[s2][threadIdx.x]);
            int p = atomicAdd(cnt, 1);
            flags[p] = nn;
            ccnt[nn] = lcc[threadIdx.x];
            v2q[nn] = __int_as_float(m & 0xFFFFFF00) - 2.0f;
            #pragma unroll
            for (int j = 0; j < MAXC; j++) cand[nn * MAXC + j] = lcand[threadIdx.x][j];
        }
    }
}

// ---------------- fp64 rescore of candidate columns (block per flagged row) ------
__launch_bounds__(256)
__global__ void k_rescan_cand(const int* __restrict__ flags, const int* __restrict__ cnt,
                              const int* __restrict__ cand, const int* __restrict__ ccnt,
                              const float* __restrict__ v2q,
                              const float* __restrict__ z, const float* __restrict__ emb,
                              const double* __restrict__ se2,
                              int* __restrict__ idx_ws, float* __restrict__ out_idx,
                              int* __restrict__ flags2, int* __restrict__ cnt2,
                              unsigned long long* __restrict__ slot, int* __restrict__ bm) {
    __shared__ double zs[DIM];
    __shared__ double wv[4];
    __shared__ int    wi[4];
    const int t = threadIdx.x, l = t & 63, w = t >> 6;
    const int F = *cnt;
    for (int f = blockIdx.x; f < F; f += gridDim.x) {
        int n = flags[f];
        int C = ccnt[n];
        int b = n >> 10, hw = n & 1023;
        __syncthreads();
        zs[t] = (double)z[(size_t)(b * DIM + t) * HW + hw];
        __syncthreads();
        double best = -2e18; int bi = 0x7fffffff;
        if (C <= MAXC) {
            double z0 = zs[l*4], z1 = zs[l*4+1], z2 = zs[l*4+2], z3 = zs[l*4+3];
            for (int cix = w; cix < C; cix += 4) {
                int k = cand[n * MAXC + cix];
                float4 ev = *(const float4*)(emb + (size_t)k * DIM + l * 4);
                double d = z0 * (double)ev.x + z1 * (double)ev.y
                         + z2 * (double)ev.z + z3 * (double)ev.w;
                #pragma unroll
                for (int o = 32; o > 0; o >>= 1) d += __shfl_down(d, o);
                if (l == 0) {
                    double qv = d / sqrt(se2[k]);
                    if (qv > best || (qv == best && k < bi)) { best = qv; bi = k; }
                }
            }
        }
        if (l == 0) { wv[w] = best; wi[w] = bi; }
        __syncthreads();
        if (t == 0) {
            bool esc = (C > MAXC);
            if (!esc) {
                double B = wv[0]; int BI = wi[0];
                #pragma unroll
                for (int x = 1; x < 4; x++)
                    if (wv[x] > B || (wv[x] == B && wi[x] < BI)) { B = wv[x]; BI = wi[x]; }
                if ((double)v2q[n] >= B - EHID) {
                    esc = true;                       // possible hidden code
                } else {
                    idx_ws[n] = BI; out_idx[n] = (float)BI;
                }
            }
            if (esc) {
                slot[n] = 0ull;
                bm[n] = 1;
                int p = atomicAdd(cnt2, 1);
                flags2[p] = n;
            }
        }
        __syncthreads();
    }
}

// ---------------- window-pruned rescan (replaces full 16k-code fullscan) ---------
// For an escaped row, the true winner k* has bf16 key >= cosW1 - 2*noise, and is
// at worst 2nd in its 256-code block -> its block's stored top-2 keys satisfy
// max(K1s,K2s) >= cosW1 - WINDOW. Rescan ONLY qualifying blocks (typically 1-3,
// ~0.5 MB instead of 16 MB), fp32 per-lane-code, exact lowest-index tiebreak via
// packed u64. W1's block always qualifies -> scanned set contains previous best.
__launch_bounds__(256)
__global__ void k_winscan(const int* __restrict__ flags2, const int* __restrict__ cnt2,
                          const int2* __restrict__ part,
                          const float* __restrict__ z, const float* __restrict__ emb,
                          const float* __restrict__ inv_e,
                          unsigned long long* __restrict__ slot) {
    __shared__ __align__(16) float zs[DIM];
    __shared__ int sK1[64], sK2[64];
    __shared__ unsigned long long wbest[4];
    const int t = threadIdx.x, l = t & 63, w = t >> 6;
    const int F = *cnt2;
    for (int f = blockIdx.x; f < F; f += gridDim.x) {
        int n = flags2[f];
        int b = n >> 10, hw = n & 1023;
        __syncthreads();
        zs[t] = z[(size_t)(b * DIM + t) * HW + hw];
        if (t < 64) {
            int2 e = part[(size_t)t * NROWS + n];
            sK1[t] = e.x; sK2[t] = e.y;
        }
        __syncthreads();
        int K1 = 0;
        #pragma unroll
        for (int s = 0; s < 64; s++) K1 = imax(K1, sK1[s]);
        float cosW1 = __int_as_float(K1 & 0xFFFFFF00) - 2.0f;
        int thr = __float_as_int((cosW1 - WINDOW) + 2.0f) & 0xFFFFFF00;
        unsigned long long best = 0ull;
        for (int s = 0; s < 64; s++) {
            if (imax(sK1[s], sK2[s]) < thr) continue;    // wave-uniform (LDS broadcast)
            int k = s * 256 + t;
            const float4* er = (const float4*)(emb + (size_t)k * DIM);
            float d0 = 0.f, d1 = 0.f, d2 = 0.f, d3 = 0.f;
            #pragma unroll
            for (int d4 = 0; d4 < 64; d4++) {
                float4 ev = er[d4];
                float4 zv = *(const float4*)&zs[d4 * 4];
                d0 += zv.x * ev.x; d1 += zv.y * ev.y;
                d2 += zv.z * ev.z; d3 += zv.w * ev.w;
            }
            float qv = ((d0 + d1) + (d2 + d3)) * inv_e[k];
            // qv in (-~25,~25); +32 -> positive, fp32 bits order-preserving.
            unsigned long long key =
                (((unsigned long long)__float_as_uint(qv + 32.0f)) << 14)
                | (unsigned long long)(0x3FFF - k);      // tie -> lowest k
            best = key > best ? key : best;
        }
        #pragma unroll
        for (int o = 32; o > 0; o >>= 1) {
            unsigned long long ob = __shfl_down(best, o);
            best = ob > best ? ob : best;
        }
        if (l == 0) wbest[w] = best;
        __syncthreads();
        if (t == 0) {
            unsigned long long B = wbest[0];
            #pragma unroll
            for (int x = 1; x < 4; x++) B = wbest[x] > B ? wbest[x] : B;
            slot[n] = B;
        }
    }
}

// ---------------- gather z_q = emb[idx] * inv_e[idx]; decode winscan rows --------
__global__ void k_zq(const int* __restrict__ idx_ws, const float* __restrict__ emb,
                     const float* __restrict__ inv_e, float* __restrict__ zq,
                     const int* __restrict__ bm, const unsigned long long* __restrict__ slot,
                     float* __restrict__ out_idx) {
    int t = threadIdx.x;
    int n = blockIdx.x * 256 + t;
    int b = n >> 10, hw = n & 1023;
    int c0 = blockIdx.y * 32;
    int id = idx_ws[n];
    if (bm[n]) {
        id = 0x3FFF - (int)(slot[n] & 0x3FFFull);
        if (blockIdx.y == 0) out_idx[n] = (float)id;
    }
    float s = inv_e[id];
    const float* er = emb + (size_t)id * DIM;
    #pragma unroll
    for (int cc = 0; cc < 32; cc += 4) {
        float4 a = *(const float4*)(er + c0 + cc);
        zq[(size_t)(b * DIM + c0 + cc + 0) * HW + hw] = a.x * s;
        zq[(size_t)(b * DIM + c0 + cc + 1) * HW + hw] = a.y * s;
        zq[(size_t)(b * DIM + c0 + cc + 2) * HW + hw] = a.z * s;
        zq[(size_t)(b * DIM + c0 + cc + 3) * HW + hw] = a.w * s;
    }
}

extern "C" void kernel_launch(void* const* d_in, const int* in_sizes, int n_in,
                              void* d_out, int out_size, void* d_ws, size_t ws_size,
                              hipStream_t stream) {
    const float* z   = (const float*)d_in[0];
    const float* emb = (const float*)d_in[1];

    unsigned short* Zh = (unsigned short*)d_ws;           // 4 MB (fragment-major)
    unsigned short* Eh = Zh + (size_t)NROWS * DIM;        // 8 MB (fragment-major)
    float*  inv_e = (float*)(Eh + (size_t)NUM_E * DIM);   // 64 KB
    float*  zpart = inv_e + NUM_E;                        // 512 KB (reused as slot later)
    int*    idx_ws = (int*)(zpart + 16 * NROWS);          // 32 KB
    double* se2   = (double*)(idx_ws + NROWS);            // 128 KB
    int*    flags = (int*)(se2 + NUM_E);                  // 32 KB
    int*    flags2 = flags + NROWS;                       // 32 KB
    int*    cand  = flags2 + NROWS;                       // 512 KB (16/row)
    int*    ccnt  = cand + NROWS * MAXC;                  // 32 KB
    float*  v2q   = (float*)(ccnt + NROWS);               // 32 KB
    int*    bm    = (int*)(v2q + NROWS);                  // 32 KB (winscan bitmap)
    int*    cnt   = bm + NROWS;                           // 4 B
    int*    cnt2  = cnt + 1;                              // 4 B
    unsigned long long* slot = (unsigned long long*)zpart; // 64 KB, reuses zpart

    float* zq      = (float*)d_out;
    float* out_idx = zq + (size_t)NROWS * DIM;
    // part (4 MB: 64 segs x 8192 rows x int2) aliases the z_q region's first half;
    // consumed by k_final + k_winscan, then overwritten by k_zq.
    int2* part = (int2*)zq;

    k_pre        <<<NUM_E / 4 + 512, 256, 0, stream>>>(z, emb, zpart, inv_e, se2, Eh, cnt, cnt2);
    k_prep_z     <<<dim3(NROWS / 64, DIM / 64), 256, 0, stream>>>(z, zpart, Zh);
    k_score      <<<(NROWS / BM) * NCB, 256, 0, stream>>>(Zh, Eh, part);
    k_final      <<<NROWS / 32, 256, 0, stream>>>(part, idx_ws, out_idx, flags, cnt,
                                                  cand, ccnt, v2q, bm);
    k_rescan_cand<<<1024, 256, 0, stream>>>(flags, cnt, cand, ccnt, v2q, z, emb, se2,
                                            idx_ws, out_idx, flags2, cnt2, slot, bm);
    k_winscan    <<<1024, 256, 0, stream>>>(flags2, cnt2, part, z, emb, inv_e, slot);
    k_zq         <<<dim3(NROWS / 256, 8), 256, 0, stream>>>(idx_ws, emb, inv_e, zq,
                                                            bm, slot, out_idx);
}